// Round 10
// baseline (698.515 us; speedup 1.0000x reference)
//
#include <hip/hip_runtime.h>
#include <hip/hip_bf16.h>
#include <math.h>

#define NNODES 50000
#define NEDGES 800000
#define DIN 768
#define DH 256
#define NCLS 4
#define NGRAPHS 64
#define SCAN_BLOCKS 196   // ceil(NNODES/256)
#define WSCHUNK 32
#define NCHUNKS ((NNODES + WSCHUNK - 1) / WSCHUNK)   // 1563

typedef __bf16 bf16x8 __attribute__((ext_vector_type(8)));
typedef float f32x4 __attribute__((ext_vector_type(4)));

static __device__ __forceinline__ float bf2f(unsigned short u) {
    union { unsigned u32; float f; } v; v.u32 = ((unsigned)u) << 16; return v.f;
}
static __device__ __forceinline__ unsigned short f2bf(float f) {
    union { float f; unsigned u; } v; v.f = f;
    unsigned r = (v.u + 0x7fffu + ((v.u >> 16) & 1u)) >> 16;
    return (unsigned short)r;
}
static __device__ __forceinline__ void unpack8(uint4 u, float* f) {
    f[0] = bf2f((unsigned short)(u.x & 0xffff)); f[1] = bf2f((unsigned short)(u.x >> 16));
    f[2] = bf2f((unsigned short)(u.y & 0xffff)); f[3] = bf2f((unsigned short)(u.y >> 16));
    f[4] = bf2f((unsigned short)(u.z & 0xffff)); f[5] = bf2f((unsigned short)(u.z >> 16));
    f[6] = bf2f((unsigned short)(u.w & 0xffff)); f[7] = bf2f((unsigned short)(u.w >> 16));
}
static __device__ __forceinline__ void acc8(uint4 u, float* f) {
    f[0] += bf2f((unsigned short)(u.x & 0xffff)); f[1] += bf2f((unsigned short)(u.x >> 16));
    f[2] += bf2f((unsigned short)(u.y & 0xffff)); f[3] += bf2f((unsigned short)(u.y >> 16));
    f[4] += bf2f((unsigned short)(u.z & 0xffff)); f[5] += bf2f((unsigned short)(u.z >> 16));
    f[6] += bf2f((unsigned short)(u.w & 0xffff)); f[7] += bf2f((unsigned short)(u.w >> 16));
}
static __device__ __forceinline__ void gload_lds16(const void* g, void* l) {
    __builtin_amdgcn_global_load_lds((const __attribute__((address_space(1))) void*)g,
                                     (__attribute__((address_space(3))) void*)l, 16, 0, 0);
}

static __device__ __forceinline__ unsigned short cload(const void* src, int i, int fp32) {
    return fp32 ? f2bf(((const float*)src)[i]) : ((const unsigned short*)src)[i];
}

// ---------------- fused prep: per-block dtype detect + canon + transposes ----------------
__global__ __launch_bounds__(256) void prep_fused(
    const unsigned short* __restrict__ x,
    const void* Win, const void* convW,
    const void* b_in, const void* convB, const void* lnG, const void* lnB,
    const void* W1, const void* W2, const void* b1, const void* b2,
    unsigned short* __restrict__ WinT, unsigned short* __restrict__ WcT,
    unsigned short* __restrict__ cw, int* __restrict__ flag)
{
    __shared__ int cnt_s;
    if (threadIdx.x == 0) cnt_s = 0;
    __syncthreads();
    {
        float v = bf2f(x[threadIdx.x]);
        unsigned long long m = __ballot(!(fabsf(v) < 1e10f));
        if ((threadIdx.x & 63) == 0) atomicAdd(&cnt_s, __popcll(m));
    }
    __syncthreads();
    const int fp32 = (cnt_s > 8);
    if (blockIdx.x == 0 && threadIdx.x == 0) flag[0] = fp32;

    const int b = blockIdx.x;
    if (b < 768) {
        int idx = b * 256 + threadIdx.x;          // DIN*DH = 196608
        int r = idx / DH, c = idx % DH;
        WinT[(size_t)c * DIN + r] = cload(Win, idx, fp32);
    } else if (b < 1536) {
        int idx = (b - 768) * 256 + threadIdx.x;  // 3*DH*DH = 196608
        int l = idx >> 16, rc = idx & 65535;
        int r = rc >> 8, c = rc & 255;
        WcT[(l << 16) + c * DH + r] = cload(convW, idx, fp32);
    } else {
        int i = (b - 1536) * 256 + threadIdx.x;   // canon, 69380 elements
        if (i >= 69380) return;
        int j = i;
        if (j < 256)  { cw[i] = cload(b_in, j, fp32); return; }  j -= 256;
        if (j < 768)  { cw[i] = cload(convB, j, fp32); return; } j -= 768;
        if (j < 768)  { cw[i] = cload(lnG, j, fp32); return; }   j -= 768;
        if (j < 768)  { cw[i] = cload(lnB, j, fp32); return; }   j -= 768;
        if (j < 65536){ cw[i] = cload(W1, j, fp32); return; }    j -= 65536;
        if (j < 1024) { cw[i] = cload(W2, j, fp32); return; }    j -= 1024;
        if (j < 256)  { cw[i] = cload(b1, j, fp32); return; }    j -= 256;
        cw[i] = cload(b2, j, fp32);
    }
}

// ---------------- diagnostic sentinel (ws too small) ----------------
__global__ void fill_sentinel(float* out, int n) {
    int i = blockIdx.x * 256 + threadIdx.x;
    if (i < n) out[i] = 1000.0f;
}

// ---------------- CSR build ----------------
__global__ void count_edges(const int* __restrict__ ei, int* __restrict__ cnt) {
    int e = blockIdx.x * 256 + threadIdx.x;
    if (e < NEDGES) atomicAdd(&cnt[ei[NEDGES + e]], 1);
}

__global__ void scan_local(const int* __restrict__ cnt, int* __restrict__ rowptr,
                           int* __restrict__ bsum) {
    __shared__ int tmp[256];
    int i = blockIdx.x * 256 + threadIdx.x;
    int v = (i < NNODES) ? cnt[i] : 0;
    tmp[threadIdx.x] = v;
    __syncthreads();
    for (int off = 1; off < 256; off <<= 1) {
        int a = (threadIdx.x >= off) ? tmp[threadIdx.x - off] : 0;
        __syncthreads();
        tmp[threadIdx.x] += a;
        __syncthreads();
    }
    if (i < NNODES) rowptr[i] = tmp[threadIdx.x] - v;  // local exclusive
    if (threadIdx.x == 255) bsum[blockIdx.x] = tmp[255];
}
__global__ void scan_bsum(const int* __restrict__ bsum, int* __restrict__ boff) {
    __shared__ int tmp[256];
    int t = threadIdx.x;
    int v = (t < SCAN_BLOCKS) ? bsum[t] : 0;
    tmp[t] = v;
    __syncthreads();
    for (int off = 1; off < 256; off <<= 1) {
        int a = (t >= off) ? tmp[t - off] : 0;
        __syncthreads();
        tmp[t] += a;
        __syncthreads();
    }
    if (t < SCAN_BLOCKS) boff[t] = tmp[t] - v;
}
__global__ void scan_finish(int* __restrict__ rowptr, const int* __restrict__ boff,
                            const int* __restrict__ cnt, float* __restrict__ dinv) {
    int i = blockIdx.x * 256 + threadIdx.x;
    if (i < NNODES) {
        rowptr[i] += boff[blockIdx.x];
        dinv[i] = rsqrtf((float)(1 + cnt[i]));  // +1 self-loop
    }
    if (i == 0) rowptr[NNODES] = NEDGES;
}

__global__ void fill_csr(const int* __restrict__ ei, const int* __restrict__ rowptr,
                         int* __restrict__ cursor, int* __restrict__ csrc) {
    int e = blockIdx.x * 256 + threadIdx.x;
    if (e < NEDGES) {
        int s = ei[e];
        int d = ei[NEDGES + e];
        int pos = rowptr[d] + atomicAdd(&cursor[d], 1);
        csrc[pos] = s;
    }
}

// ---- sort each node's src list ascending (perf hint for aggregate L2 locality).
// Blocks dispatch ~in node order and degrees concentrate near 16 (Poisson), so
// ascending-src walks make the machine-wide gather working set at edge-round k
// a quantile window of m instead of all 25.6 MB -> higher per-XCD L2 hit rate.
// deg > 48 (P ~ 1e-11) is skipped: sorting is optional for correctness.
__global__ __launch_bounds__(256) void sort_csr(const int* __restrict__ rowptr,
                                                int* __restrict__ csrc) {
    __shared__ int buf[256 * 48];   // 48 KB
    int node = blockIdx.x * 256 + threadIdx.x;
    if (node >= NNODES) return;
    int kb = rowptr[node], ke = rowptr[node + 1];
    int d = ke - kb;
    if (d <= 1 || d > 48) return;
    int* b = &buf[threadIdx.x * 48];
    for (int i = 0; i < d; ++i) b[i] = csrc[kb + i];
    for (int i = 1; i < d; ++i) {
        int v = b[i]; int j = i - 1;
        while (j >= 0 && b[j] > v) { b[j + 1] = b[j]; --j; }
        b[j + 1] = v;
    }
    for (int i = 0; i < d; ++i) csrc[kb + i] = b[i];
}

// ---- INPUT GEMM (K=768, A fp32|bf16 runtime flag). R7-measured-best (105us):
// triple-buffered LDS, prefetch distance 2, raw s_barrier with counted vmcnt.
// 7 structural variants bracket this kernel at >=105us — treated as its floor.
__global__ __launch_bounds__(256, 2) void gemm_in(
    const void* __restrict__ Araw, const int* __restrict__ dflag,
    const unsigned short* __restrict__ Bt, const unsigned short* __restrict__ bias,
    unsigned short* __restrict__ C, int M, int K)
{
    __shared__ __align__(16) char As[3][8192];
    __shared__ __align__(16) char Bs[3][16384];

    const int af32 = dflag[0];
    const int m0 = blockIdx.x * 64;
    const int t = threadIdx.x, wave = t >> 6, lane = t & 63;
    const int quad = lane >> 4, l16 = lane & 15;

    const char* bsrc[4];
#pragma unroll
    for (int li = 0; li < 4; ++li) {
        int c = wave * 256 + li * 64 + lane;
        int r = c >> 2, p = c & 3;
        int l = p ^ ((r >> 1) & 3);
        bsrc[li] = (const char*)Bt + ((size_t)r * K + l * 8) * 2;
    }
    const char* asrc[2];
    if (af32) {
#pragma unroll
        for (int li = 0; li < 2; ++li) {
            int c = wave * 128 + li * 64 + lane;
            int r = c >> 3, p = c & 7;
            int l = p ^ (r & 7);
            int rg = min(m0 + r, M - 1);
            asrc[li] = (const char*)Araw + ((size_t)rg * K + l * 4) * 4;
        }
    } else {
        int c = wave * 64 + lane;
        int r = c >> 2, p = c & 3;
        int l = p ^ ((r >> 1) & 3);
        int rg = min(m0 + r, M - 1);
        asrc[0] = (const char*)Araw + ((size_t)rg * K + l * 8) * 2;
        asrc[1] = asrc[0];
    }

    auto stage = [&](int tile, int bi) {
        const size_t k0 = (size_t)tile * 32;
#pragma unroll
        for (int li = 0; li < 4; ++li)
            gload_lds16(bsrc[li] + k0 * 2, &Bs[bi][(wave * 256 + li * 64) * 16]);
        if (af32) {
            gload_lds16(asrc[0] + k0 * 4, &As[bi][(wave * 128) * 16]);
            gload_lds16(asrc[1] + k0 * 4, &As[bi][(wave * 128 + 64) * 16]);
        } else {
            gload_lds16(asrc[0] + k0 * 2, &As[bi][(wave * 64) * 16]);
        }
    };

    f32x4 acc[4][4];
#pragma unroll
    for (int i = 0; i < 4; i++)
#pragma unroll
        for (int j = 0; j < 4; j++) acc[i][j] = (f32x4){0.f, 0.f, 0.f, 0.f};

    stage(0, 0);
    stage(1, 1);
    if (af32) asm volatile("s_waitcnt vmcnt(6)" ::: "memory");
    else      asm volatile("s_waitcnt vmcnt(5)" ::: "memory");
    __builtin_amdgcn_sched_barrier(0);
    __builtin_amdgcn_s_barrier();
    __builtin_amdgcn_sched_barrier(0);

    const int nt = K / 32;
    for (int tt = 0; tt < nt; ++tt) {
        const int bi = tt % 3;
        const bool deep = (tt + 2) < nt;
        if (deep) stage(tt + 2, (tt + 2) % 3);

        const char* as_ = As[bi];
        const char* bs_ = Bs[bi];
        bf16x8 afv[4], bfv[4];
        if (af32) {
#pragma unroll
            for (int i = 0; i < 4; i++) {
                const int row = 16 * i + l16;
                const int ph0 = (quad * 2) ^ (row & 7);
                float4 x0 = *(const float4*)(as_ + row * 128 + ph0 * 16);
                float4 x1 = *(const float4*)(as_ + row * 128 + (ph0 ^ 1) * 16);
                union { bf16x8 v; __bf16 e[8]; } u;
                u.e[0] = (__bf16)x0.x; u.e[1] = (__bf16)x0.y;
                u.e[2] = (__bf16)x0.z; u.e[3] = (__bf16)x0.w;
                u.e[4] = (__bf16)x1.x; u.e[5] = (__bf16)x1.y;
                u.e[6] = (__bf16)x1.z; u.e[7] = (__bf16)x1.w;
                afv[i] = u.v;
            }
        } else {
            const int ph = (quad ^ ((l16 >> 1) & 3)) * 16;
#pragma unroll
            for (int i = 0; i < 4; i++)
                afv[i] = *(const bf16x8*)(as_ + (16 * i + l16) * 64 + ph);
        }
        {
            const int ph = (quad ^ ((l16 >> 1) & 3)) * 16;
#pragma unroll
            for (int j = 0; j < 4; j++)
                bfv[j] = *(const bf16x8*)(bs_ + (wave * 64 + 16 * j + l16) * 64 + ph);
        }
#pragma unroll
        for (int i = 0; i < 4; i++)
#pragma unroll
            for (int j = 0; j < 4; j++)
                acc[i][j] = __builtin_amdgcn_mfma_f32_16x16x32_bf16(afv[i], bfv[j], acc[i][j], 0, 0, 0);

        if (deep) {
            if (af32) asm volatile("s_waitcnt vmcnt(6)" ::: "memory");
            else      asm volatile("s_waitcnt vmcnt(5)" ::: "memory");
        } else {
            asm volatile("s_waitcnt vmcnt(0)" ::: "memory");
        }
        __builtin_amdgcn_sched_barrier(0);
        __builtin_amdgcn_s_barrier();
        __builtin_amdgcn_sched_barrier(0);
    }

#pragma unroll
    for (int j = 0; j < 4; j++) {
        const int gc = wave * 64 + 16 * j + l16;
        const float bv = bf2f(bias[gc]);
#pragma unroll
        for (int i = 0; i < 4; i++) {
#pragma unroll
            for (int rr = 0; rr < 4; rr++) {
                int gr = m0 + 16 * i + quad * 4 + rr;
                if (gr < M) C[(size_t)gr * 256 + gc] = f2bf(acc[i][j][rr] + bv);
            }
        }
    }
}

// ---- CONV GEMM, weight-stationary (R6-verified): B staged to LDS once,
// A streamed in 32-row chunks, grid=256 persistent, 1 block/CU.
__global__ __launch_bounds__(512, 1) void gemm_ws(
    const unsigned short* __restrict__ A,   // [M,256] bf16
    const unsigned short* __restrict__ Bt,  // [256,256] bf16 [col][k]
    const float* __restrict__ prescale,     // dinv
    unsigned short* __restrict__ C, int M)
{
    __shared__ __align__(16) unsigned short Bs[256 * 256];       // 128 KB
    __shared__ __align__(16) unsigned short As[WSCHUNK * 256];   // 16 KB

    const int t = threadIdx.x;            // 0..511
    const int wave = t >> 6, lane = t & 63;
    const int quad = lane >> 4, l16 = lane & 15;
    const int rf = wave & 1;              // 16-row group within chunk
    const int cg = wave >> 1;             // 64-col group

    for (int it = 0; it < 16; ++it) {
        int id = it * 512 + t;
        int col = id >> 5, p = id & 31;
        int l = p ^ (col & 31);
        gload_lds16(Bt + col * 256 + l * 8, (char*)Bs + id * 16);
    }
    {
        const int rbs = blockIdx.x * WSCHUNK;
#pragma unroll
        for (int it = 0; it < 2; ++it) {
            int id = it * 512 + t;
            int row = id >> 5, p = id & 31;
            int l = p ^ (row & 31);
            int rg = min(rbs + row, M - 1);
            gload_lds16(A + (size_t)rg * 256 + l * 8, (char*)As + id * 16);
        }
    }
    __syncthreads();   // drains all DMA: B + A0 ready

    for (int c = blockIdx.x; c < NCHUNKS; c += 256) {
        f32x4 acc[4];
#pragma unroll
        for (int j = 0; j < 4; ++j) acc[j] = (f32x4){0.f, 0.f, 0.f, 0.f};

        const int arow = rf * 16 + l16;
#pragma unroll
        for (int ks = 0; ks < 8; ++ks) {
            const int s = ks * 4 + quad;
            bf16x8 af = *(const bf16x8*)((const char*)As + arow * 512 + ((s ^ (arow & 31)) * 16));
#pragma unroll
            for (int j = 0; j < 4; ++j) {
                const int col = cg * 64 + j * 16 + l16;
                bf16x8 bf = *(const bf16x8*)((const char*)Bs + col * 512 + ((s ^ (col & 31)) * 16));
                acc[j] = __builtin_amdgcn_mfma_f32_16x16x32_bf16(af, bf, acc[j], 0, 0, 0);
            }
        }
        __syncthreads();   // all waves done reading As

        const int cn = c + 256;
        if (cn < NCHUNKS) {
            const int rbs = cn * WSCHUNK;
#pragma unroll
            for (int it = 0; it < 2; ++it) {
                int id = it * 512 + t;
                int row = id >> 5, p = id & 31;
                int l = p ^ (row & 31);
                int rg = min(rbs + row, M - 1);
                gload_lds16(A + (size_t)rg * 256 + l * 8, (char*)As + id * 16);
            }
        }
        const int rb = c * WSCHUNK;
#pragma unroll
        for (int r = 0; r < 4; ++r) {
            const int gr = rb + rf * 16 + quad * 4 + r;
            if (gr < M) {
                const float sc = prescale[gr];
#pragma unroll
                for (int j = 0; j < 4; ++j) {
                    const int gc = cg * 64 + j * 16 + l16;
                    C[(size_t)gr * 256 + gc] = f2bf(acc[j][r] * sc);
                }
            }
        }
        __syncthreads();   // next A DMA drained; As ready for next iter
    }
}

// ------- fused: CSR gather + self-loop + bias + residual + ReLU + LayerNorm -------
// m is PRE-SCALED: m'[v] = dinv[v] * (h@W)[v], so
// h_new[v] = dinv[v] * (sum_{s in N(v)} m'[s] + m'[v]) + convB.
// src lists are SORTED ascending (sort_csr) for L2 locality.
__global__ __launch_bounds__(256) void aggregate_ln(
    const int* __restrict__ rowptr, const int* __restrict__ csrc,
    const float* __restrict__ dinv, const unsigned short* __restrict__ m,
    const unsigned short* __restrict__ convB,
    const unsigned short* __restrict__ lnG, const unsigned short* __restrict__ lnB,
    unsigned short* __restrict__ h)
{
    const int half = threadIdx.x >> 5;
    const int lane = threadIdx.x & 31;
    const int node = blockIdx.x * 8 + half;  // NNODES % 8 == 0
    const float di = dinv[node];
    const size_t base = (size_t)node * DH + lane * 8;
    const size_t lo = lane * 8;

    float v0[8], v1[8];
    unpack8(*(const uint4*)(m + base), v0);   // self term m'[v]
#pragma unroll
    for (int j = 0; j < 8; j++) v1[j] = 0.f;

    const int kb = rowptr[node], ke = rowptr[node + 1];
    int k = kb;
    for (; k + 8 <= ke; k += 8) {
        int s0 = csrc[k],     s1 = csrc[k + 1], s2 = csrc[k + 2], s3 = csrc[k + 3];
        int s4 = csrc[k + 4], s5 = csrc[k + 5], s6 = csrc[k + 6], s7 = csrc[k + 7];
        uint4 r0 = *(const uint4*)(m + (size_t)s0 * DH + lo);
        uint4 r1 = *(const uint4*)(m + (size_t)s1 * DH + lo);
        uint4 r2 = *(const uint4*)(m + (size_t)s2 * DH + lo);
        uint4 r3 = *(const uint4*)(m + (size_t)s3 * DH + lo);
        uint4 r4 = *(const uint4*)(m + (size_t)s4 * DH + lo);
        uint4 r5 = *(const uint4*)(m + (size_t)s5 * DH + lo);
        uint4 r6 = *(const uint4*)(m + (size_t)s6 * DH + lo);
        uint4 r7 = *(const uint4*)(m + (size_t)s7 * DH + lo);
        acc8(r0, v0); acc8(r1, v1); acc8(r2, v0); acc8(r3, v1);
        acc8(r4, v0); acc8(r5, v1); acc8(r6, v0); acc8(r7, v1);
    }
    for (; k + 2 <= ke; k += 2) {
        int s0 = csrc[k], s1 = csrc[k + 1];
        uint4 r0 = *(const uint4*)(m + (size_t)s0 * DH + lo);
        uint4 r1 = *(const uint4*)(m + (size_t)s1 * DH + lo);
        acc8(r0, v0); acc8(r1, v1);
    }
    if (k < ke) {
        uint4 r0 = *(const uint4*)(m + (size_t)csrc[k] * DH + lo);
        acc8(r0, v0);
    }
#pragma unroll
    for (int j = 0; j < 8; j++) v0[j] = (v0[j] + v1[j]) * di;

    float hv[8], cv[8];
    unpack8(*(const uint4*)(h + base), hv);
    unpack8(*(const uint4*)(convB + lo), cv);
    float s1 = 0.f, s2 = 0.f;
#pragma unroll
    for (int j = 0; j < 8; j++) {
        v0[j] = fmaxf(v0[j] + cv[j] + hv[j], 0.f);
        s1 += v0[j];
        s2 += v0[j] * v0[j];
    }
#pragma unroll
    for (int off = 16; off > 0; off >>= 1) {
        s1 += __shfl_xor(s1, off, 32);
        s2 += __shfl_xor(s2, off, 32);
    }
    const float mu = s1 * (1.f / 256.f);
    const float var = s2 * (1.f / 256.f) - mu * mu;
    const float rs = rsqrtf(var + 1e-5f);
    float gv[8], bv[8];
    unpack8(*(const uint4*)(lnG + lo), gv);
    unpack8(*(const uint4*)(lnB + lo), bv);
    unsigned short o[8];
#pragma unroll
    for (int j = 0; j < 8; j++) o[j] = f2bf((v0[j] - mu) * rs * gv[j] + bv[j]);
    uint4 outp;
    outp.x = (unsigned)o[0] | ((unsigned)o[1] << 16);
    outp.y = (unsigned)o[2] | ((unsigned)o[3] << 16);
    outp.z = (unsigned)o[4] | ((unsigned)o[5] << 16);
    outp.w = (unsigned)o[6] | ((unsigned)o[7] << 16);
    *(uint4*)(h + base) = outp;
}

// ---- pooling: coalesced row reads + inline binary search on sorted batch ----
#define PSPLIT 8
__global__ __launch_bounds__(256) void pool_partial(
    const unsigned short* __restrict__ h, const int* __restrict__ batch,
    float* __restrict__ pg)
{
    __shared__ float red[8][DH];
    __shared__ int bounds[2];
    const int b = blockIdx.x >> 3, split = blockIdx.x & 7;
    if (threadIdx.x < 2) {
        int target = b + threadIdx.x;
        int lo = 0, hi = NNODES;
        while (lo < hi) { int mid = (lo + hi) >> 1; if (batch[mid] < target) lo = mid + 1; else hi = mid; }
        bounds[threadIdx.x] = lo;
    }
    __syncthreads();
    const int i0 = bounds[0], i1 = bounds[1];
    const int g = threadIdx.x >> 5, lane = threadIdx.x & 31;
    const int len = i1 - i0;
    const int c0 = i0 + (int)(((long)len * split) >> 3);
    const int c1 = i0 + (int)(((long)len * (split + 1)) >> 3);
    float mx[8];
#pragma unroll
    for (int j = 0; j < 8; ++j) mx[j] = -INFINITY;
    for (int r = c0 + g; r < c1; r += 8) {
        uint4 v = *(const uint4*)(h + (size_t)r * DH + lane * 8);
        float f[8];
        unpack8(v, f);
#pragma unroll
        for (int j = 0; j < 8; ++j) mx[j] = fmaxf(mx[j], f[j]);
    }
#pragma unroll
    for (int j = 0; j < 8; ++j) red[g][lane * 8 + j] = mx[j];
    __syncthreads();
    const int f = threadIdx.x;
    float m0 = fmaxf(fmaxf(red[0][f], red[1][f]), fmaxf(red[2][f], red[3][f]));
    float m1 = fmaxf(fmaxf(red[4][f], red[5][f]), fmaxf(red[6][f], red[7][f]));
    pg[(size_t)blockIdx.x * DH + f] = fmaxf(m0, m1);
}
__global__ __launch_bounds__(256) void pool_reduce(const float* __restrict__ pg,
                                                   float* __restrict__ g) {
    const int b = blockIdx.x, f = threadIdx.x;
    float mx = -INFINITY;
#pragma unroll
    for (int j = 0; j < PSPLIT; ++j) mx = fmaxf(mx, pg[(size_t)(b * PSPLIT + j) * DH + f]);
    g[b * DH + f] = mx;
}

// ---------------- classifier: out = relu(g@W1+b1)@W2+b2 ----------------
__global__ __launch_bounds__(256) void classifier(
    const float* __restrict__ g, const unsigned short* __restrict__ W1,
    const unsigned short* __restrict__ b1, const unsigned short* __restrict__ W2,
    const unsigned short* __restrict__ b2, void* __restrict__ outv,
    const int* __restrict__ flag)
{
    __shared__ float gz[DH];
    __shared__ float zz[DH];
    const int b = blockIdx.x, t = threadIdx.x;
    gz[t] = g[b * DH + t];
    __syncthreads();
    float s = bf2f(b1[t]);
    for (int k = 0; k < DH; ++k) s += gz[k] * bf2f(W1[k * DH + t]);
    zz[t] = fmaxf(s, 0.f);
    __syncthreads();
    if (t < NCLS) {
        float s2 = bf2f(b2[t]);
        for (int k = 0; k < DH; ++k) s2 += zz[k] * bf2f(W2[k * NCLS + t]);
        if (flag[0]) ((float*)outv)[b * NCLS + t] = s2;
        else ((unsigned short*)outv)[b * NCLS + t] = f2bf(s2);
    }
}

extern "C" void kernel_launch(void* const* d_in, const int* in_sizes, int n_in,
                              void* d_out, int out_size, void* d_ws, size_t ws_size,
                              hipStream_t stream)
{
    const void* x      = d_in[0];
    const int* ei      = (const int*)d_in[1];
    const int* batch   = (const int*)d_in[2];
    const void* Win    = d_in[3];
    const void* b_in   = d_in[4];
    const void* convW  = d_in[5];
    const void* convB  = d_in[6];
    const void* lnG    = d_in[7];
    const void* lnB    = d_in[8];
    const void* W1     = d_in[9];
    const void* b1     = d_in[10];
    const void* W2     = d_in[11];
    const void* b2     = d_in[12];

    // workspace layout (bytes), 16B aligned
    char* ws = (char*)d_ws;
    unsigned short* h   = (unsigned short*)(ws + 0);          // 25,600,000
    unsigned short* m   = (unsigned short*)(ws + 25600000);   // 25,600,000
    int* csrc           = (int*)(ws + 51200000);              //  3,200,000
    int* rowptr         = (int*)(ws + 54400000);              //    200,016
    int* cnt            = (int*)(ws + 54600016);              //    200,000
    int* cursor         = (int*)(ws + 54800016);              //    200,000
    float* dinv         = (float*)(ws + 55000016);            //    200,000
    unsigned short* cw  = (unsigned short*)(ws + 55200016);   //    138,768
    unsigned short* WinT= (unsigned short*)(ws + 55338784);   //    393,216
    unsigned short* WcT = (unsigned short*)(ws + 55732000);   //    393,216
    float* g            = (float*)(ws + 56125216);            //     65,536
    float* pg           = (float*)(ws + 56190752);            //    524,288
    int* bsum           = (int*)(ws + 56715312);              //        800
    int* boff           = (int*)(ws + 56716112);              //        800
    int* flag           = (int*)(ws + 56716912);              //         16
    const size_t NEED   = 56716928;
    if (ws_size < NEED) {
        fill_sentinel<<<(out_size / 2 + 255) / 256, 256, 0, stream>>>((float*)d_out, out_size / 2);
        return;
    }

    // canonical small weights (bf16 element offsets within cw)
    unsigned short* cBin   = cw + 0;
    unsigned short* cConvB = cw + 256;
    unsigned short* cLnG   = cw + 1024;
    unsigned short* cLnB   = cw + 1792;
    unsigned short* cW1    = cw + 2560;
    unsigned short* cW2    = cw + 68096;
    unsigned short* cB1    = cw + 69120;
    unsigned short* cB2    = cw + 69376;

    // ---- fused prep: dtype detect + canon + both transposes (1 launch) ----
    prep_fused<<<1808, 256, 0, stream>>>((const unsigned short*)x, Win, convW,
                                         b_in, convB, lnG, lnB, W1, W2, b1, b2,
                                         WinT, WcT, cw, flag);

    // ---- CSR build (dst-sorted) + degrees ----
    hipMemsetAsync(cnt, 0, 400000, stream);  // cnt AND cursor (contiguous)
    count_edges<<<(NEDGES + 255) / 256, 256, 0, stream>>>(ei, cnt);
    scan_local<<<SCAN_BLOCKS, 256, 0, stream>>>(cnt, rowptr, bsum);
    scan_bsum<<<1, 256, 0, stream>>>(bsum, boff);
    scan_finish<<<SCAN_BLOCKS, 256, 0, stream>>>(rowptr, boff, cnt, dinv);
    fill_csr<<<(NEDGES + 255) / 256, 256, 0, stream>>>(ei, rowptr, cursor, csrc);
    sort_csr<<<SCAN_BLOCKS, 256, 0, stream>>>(rowptr, csrc);

    // ---- h = x @ W_in + b_in ----
    gemm_in<<<(NNODES + 63) / 64, 256, 0, stream>>>(x, flag, WinT, cBin, h, NNODES, DIN);

    // ---- 3 GCN layers: m' = dinv * (h@W)  then  h = LN(relu(dinv*(sum m') + b + h))
    for (int i = 0; i < 3; i++) {
        gemm_ws<<<256, 512, 0, stream>>>(h, WcT + i * DH * DH, dinv, m, NNODES);
        aggregate_ln<<<NNODES / 8, 256, 0, stream>>>(
            rowptr, csrc, dinv, m, cConvB + i * DH, cLnG + i * DH, cLnB + i * DH, h);
    }

    // ---- global max pool + classifier ----
    pool_partial<<<NGRAPHS * PSPLIT, 256, 0, stream>>>(h, batch, pg);
    pool_reduce<<<NGRAPHS, 256, 0, stream>>>(pg, g);
    classifier<<<NGRAPHS, 256, 0, stream>>>(g, cW1, cB1, cW2, cB2, d_out, flag);
}

// Round 11
// 651.234 us; speedup vs baseline: 1.0726x; 1.0726x over previous
//
#include <hip/hip_runtime.h>
#include <hip/hip_bf16.h>
#include <math.h>

#define NNODES 50000
#define NEDGES 800000
#define DIN 768
#define DH 256
#define NCLS 4
#define NGRAPHS 64
#define SCAN_BLOCKS 196   // ceil(NNODES/256)
#define WSCHUNK 32
#define NCHUNKS ((NNODES + WSCHUNK - 1) / WSCHUNK)   // 1563

typedef __bf16 bf16x8 __attribute__((ext_vector_type(8)));
typedef float f32x4 __attribute__((ext_vector_type(4)));

static __device__ __forceinline__ float bf2f(unsigned short u) {
    union { unsigned u32; float f; } v; v.u32 = ((unsigned)u) << 16; return v.f;
}
static __device__ __forceinline__ unsigned short f2bf(float f) {
    union { float f; unsigned u; } v; v.f = f;
    unsigned r = (v.u + 0x7fffu + ((v.u >> 16) & 1u)) >> 16;
    return (unsigned short)r;
}
static __device__ __forceinline__ void unpack8(uint4 u, float* f) {
    f[0] = bf2f((unsigned short)(u.x & 0xffff)); f[1] = bf2f((unsigned short)(u.x >> 16));
    f[2] = bf2f((unsigned short)(u.y & 0xffff)); f[3] = bf2f((unsigned short)(u.y >> 16));
    f[4] = bf2f((unsigned short)(u.z & 0xffff)); f[5] = bf2f((unsigned short)(u.z >> 16));
    f[6] = bf2f((unsigned short)(u.w & 0xffff)); f[7] = bf2f((unsigned short)(u.w >> 16));
}
static __device__ __forceinline__ void acc8(uint4 u, float* f) {
    f[0] += bf2f((unsigned short)(u.x & 0xffff)); f[1] += bf2f((unsigned short)(u.x >> 16));
    f[2] += bf2f((unsigned short)(u.y & 0xffff)); f[3] += bf2f((unsigned short)(u.y >> 16));
    f[4] += bf2f((unsigned short)(u.z & 0xffff)); f[5] += bf2f((unsigned short)(u.z >> 16));
    f[6] += bf2f((unsigned short)(u.w & 0xffff)); f[7] += bf2f((unsigned short)(u.w >> 16));
}
static __device__ __forceinline__ void gload_lds16(const void* g, void* l) {
    __builtin_amdgcn_global_load_lds((const __attribute__((address_space(1))) void*)g,
                                     (__attribute__((address_space(3))) void*)l, 16, 0, 0);
}

static __device__ __forceinline__ unsigned short cload(const void* src, int i, int fp32) {
    return fp32 ? f2bf(((const float*)src)[i]) : ((const unsigned short*)src)[i];
}

// ---------------- fused prep: per-block dtype detect + canon + transposes ----------------
__global__ __launch_bounds__(256) void prep_fused(
    const unsigned short* __restrict__ x,
    const void* Win, const void* convW,
    const void* b_in, const void* convB, const void* lnG, const void* lnB,
    const void* W1, const void* W2, const void* b1, const void* b2,
    unsigned short* __restrict__ WinT, unsigned short* __restrict__ WcT,
    unsigned short* __restrict__ cw, int* __restrict__ flag)
{
    __shared__ int cnt_s;
    if (threadIdx.x == 0) cnt_s = 0;
    __syncthreads();
    {
        float v = bf2f(x[threadIdx.x]);
        unsigned long long m = __ballot(!(fabsf(v) < 1e10f));
        if ((threadIdx.x & 63) == 0) atomicAdd(&cnt_s, __popcll(m));
    }
    __syncthreads();
    const int fp32 = (cnt_s > 8);
    if (blockIdx.x == 0 && threadIdx.x == 0) flag[0] = fp32;

    const int b = blockIdx.x;
    if (b < 768) {
        int idx = b * 256 + threadIdx.x;          // DIN*DH = 196608
        int r = idx / DH, c = idx % DH;
        WinT[(size_t)c * DIN + r] = cload(Win, idx, fp32);
    } else if (b < 1536) {
        int idx = (b - 768) * 256 + threadIdx.x;  // 3*DH*DH = 196608
        int l = idx >> 16, rc = idx & 65535;
        int r = rc >> 8, c = rc & 255;
        WcT[(l << 16) + c * DH + r] = cload(convW, idx, fp32);
    } else {
        int i = (b - 1536) * 256 + threadIdx.x;   // canon, 69380 elements
        if (i >= 69380) return;
        int j = i;
        if (j < 256)  { cw[i] = cload(b_in, j, fp32); return; }  j -= 256;
        if (j < 768)  { cw[i] = cload(convB, j, fp32); return; } j -= 768;
        if (j < 768)  { cw[i] = cload(lnG, j, fp32); return; }   j -= 768;
        if (j < 768)  { cw[i] = cload(lnB, j, fp32); return; }   j -= 768;
        if (j < 65536){ cw[i] = cload(W1, j, fp32); return; }    j -= 65536;
        if (j < 1024) { cw[i] = cload(W2, j, fp32); return; }    j -= 1024;
        if (j < 256)  { cw[i] = cload(b1, j, fp32); return; }    j -= 256;
        cw[i] = cload(b2, j, fp32);
    }
}

// ---------------- diagnostic sentinel (ws too small) ----------------
__global__ void fill_sentinel(float* out, int n) {
    int i = blockIdx.x * 256 + threadIdx.x;
    if (i < n) out[i] = 1000.0f;
}

// ---------------- CSR build ----------------
__global__ void count_edges(const int* __restrict__ ei, int* __restrict__ cnt) {
    int e = blockIdx.x * 256 + threadIdx.x;
    if (e < NEDGES) atomicAdd(&cnt[ei[NEDGES + e]], 1);
}

__global__ void scan_local(const int* __restrict__ cnt, int* __restrict__ rowptr,
                           int* __restrict__ bsum) {
    __shared__ int tmp[256];
    int i = blockIdx.x * 256 + threadIdx.x;
    int v = (i < NNODES) ? cnt[i] : 0;
    tmp[threadIdx.x] = v;
    __syncthreads();
    for (int off = 1; off < 256; off <<= 1) {
        int a = (threadIdx.x >= off) ? tmp[threadIdx.x - off] : 0;
        __syncthreads();
        tmp[threadIdx.x] += a;
        __syncthreads();
    }
    if (i < NNODES) rowptr[i] = tmp[threadIdx.x] - v;  // local exclusive
    if (threadIdx.x == 255) bsum[blockIdx.x] = tmp[255];
}
__global__ void scan_bsum(const int* __restrict__ bsum, int* __restrict__ boff) {
    __shared__ int tmp[256];
    int t = threadIdx.x;
    int v = (t < SCAN_BLOCKS) ? bsum[t] : 0;
    tmp[t] = v;
    __syncthreads();
    for (int off = 1; off < 256; off <<= 1) {
        int a = (t >= off) ? tmp[t - off] : 0;
        __syncthreads();
        tmp[t] += a;
        __syncthreads();
    }
    if (t < SCAN_BLOCKS) boff[t] = tmp[t] - v;
}
__global__ void scan_finish(int* __restrict__ rowptr, const int* __restrict__ boff,
                            const int* __restrict__ cnt, float* __restrict__ dinv) {
    int i = blockIdx.x * 256 + threadIdx.x;
    if (i < NNODES) {
        rowptr[i] += boff[blockIdx.x];
        dinv[i] = rsqrtf((float)(1 + cnt[i]));  // +1 self-loop
    }
    if (i == 0) rowptr[NNODES] = NEDGES;
}

__global__ void fill_csr(const int* __restrict__ ei, const int* __restrict__ rowptr,
                         int* __restrict__ cursor, int* __restrict__ csrc) {
    int e = blockIdx.x * 256 + threadIdx.x;
    if (e < NEDGES) {
        int s = ei[e];
        int d = ei[NEDGES + e];
        int pos = rowptr[d] + atomicAdd(&cursor[d], 1);
        csrc[pos] = s;
    }
}

// ---- INPUT GEMM (K=768, A fp32|bf16 runtime flag). R7-measured-best (105us):
// triple-buffered LDS, prefetch distance 2, raw s_barrier with counted vmcnt.
// 7 structural variants bracket this kernel at >=105us — treated as its floor.
__global__ __launch_bounds__(256, 2) void gemm_in(
    const void* __restrict__ Araw, const int* __restrict__ dflag,
    const unsigned short* __restrict__ Bt, const unsigned short* __restrict__ bias,
    unsigned short* __restrict__ C, int M, int K)
{
    __shared__ __align__(16) char As[3][8192];
    __shared__ __align__(16) char Bs[3][16384];

    const int af32 = dflag[0];
    const int m0 = blockIdx.x * 64;
    const int t = threadIdx.x, wave = t >> 6, lane = t & 63;
    const int quad = lane >> 4, l16 = lane & 15;

    const char* bsrc[4];
#pragma unroll
    for (int li = 0; li < 4; ++li) {
        int c = wave * 256 + li * 64 + lane;
        int r = c >> 2, p = c & 3;
        int l = p ^ ((r >> 1) & 3);
        bsrc[li] = (const char*)Bt + ((size_t)r * K + l * 8) * 2;
    }
    const char* asrc[2];
    if (af32) {
#pragma unroll
        for (int li = 0; li < 2; ++li) {
            int c = wave * 128 + li * 64 + lane;
            int r = c >> 3, p = c & 7;
            int l = p ^ (r & 7);
            int rg = min(m0 + r, M - 1);
            asrc[li] = (const char*)Araw + ((size_t)rg * K + l * 4) * 4;
        }
    } else {
        int c = wave * 64 + lane;
        int r = c >> 2, p = c & 3;
        int l = p ^ ((r >> 1) & 3);
        int rg = min(m0 + r, M - 1);
        asrc[0] = (const char*)Araw + ((size_t)rg * K + l * 8) * 2;
        asrc[1] = asrc[0];
    }

    auto stage = [&](int tile, int bi) {
        const size_t k0 = (size_t)tile * 32;
#pragma unroll
        for (int li = 0; li < 4; ++li)
            gload_lds16(bsrc[li] + k0 * 2, &Bs[bi][(wave * 256 + li * 64) * 16]);
        if (af32) {
            gload_lds16(asrc[0] + k0 * 4, &As[bi][(wave * 128) * 16]);
            gload_lds16(asrc[1] + k0 * 4, &As[bi][(wave * 128 + 64) * 16]);
        } else {
            gload_lds16(asrc[0] + k0 * 2, &As[bi][(wave * 64) * 16]);
        }
    };

    f32x4 acc[4][4];
#pragma unroll
    for (int i = 0; i < 4; i++)
#pragma unroll
        for (int j = 0; j < 4; j++) acc[i][j] = (f32x4){0.f, 0.f, 0.f, 0.f};

    stage(0, 0);
    stage(1, 1);
    if (af32) asm volatile("s_waitcnt vmcnt(6)" ::: "memory");
    else      asm volatile("s_waitcnt vmcnt(5)" ::: "memory");
    __builtin_amdgcn_sched_barrier(0);
    __builtin_amdgcn_s_barrier();
    __builtin_amdgcn_sched_barrier(0);

    const int nt = K / 32;
    for (int tt = 0; tt < nt; ++tt) {
        const int bi = tt % 3;
        const bool deep = (tt + 2) < nt;
        if (deep) stage(tt + 2, (tt + 2) % 3);

        const char* as_ = As[bi];
        const char* bs_ = Bs[bi];
        bf16x8 afv[4], bfv[4];
        if (af32) {
#pragma unroll
            for (int i = 0; i < 4; i++) {
                const int row = 16 * i + l16;
                const int ph0 = (quad * 2) ^ (row & 7);
                float4 x0 = *(const float4*)(as_ + row * 128 + ph0 * 16);
                float4 x1 = *(const float4*)(as_ + row * 128 + (ph0 ^ 1) * 16);
                union { bf16x8 v; __bf16 e[8]; } u;
                u.e[0] = (__bf16)x0.x; u.e[1] = (__bf16)x0.y;
                u.e[2] = (__bf16)x0.z; u.e[3] = (__bf16)x0.w;
                u.e[4] = (__bf16)x1.x; u.e[5] = (__bf16)x1.y;
                u.e[6] = (__bf16)x1.z; u.e[7] = (__bf16)x1.w;
                afv[i] = u.v;
            }
        } else {
            const int ph = (quad ^ ((l16 >> 1) & 3)) * 16;
#pragma unroll
            for (int i = 0; i < 4; i++)
                afv[i] = *(const bf16x8*)(as_ + (16 * i + l16) * 64 + ph);
        }
        {
            const int ph = (quad ^ ((l16 >> 1) & 3)) * 16;
#pragma unroll
            for (int j = 0; j < 4; j++)
                bfv[j] = *(const bf16x8*)(bs_ + (wave * 64 + 16 * j + l16) * 64 + ph);
        }
#pragma unroll
        for (int i = 0; i < 4; i++)
#pragma unroll
            for (int j = 0; j < 4; j++)
                acc[i][j] = __builtin_amdgcn_mfma_f32_16x16x32_bf16(afv[i], bfv[j], acc[i][j], 0, 0, 0);

        if (deep) {
            if (af32) asm volatile("s_waitcnt vmcnt(6)" ::: "memory");
            else      asm volatile("s_waitcnt vmcnt(5)" ::: "memory");
        } else {
            asm volatile("s_waitcnt vmcnt(0)" ::: "memory");
        }
        __builtin_amdgcn_sched_barrier(0);
        __builtin_amdgcn_s_barrier();
        __builtin_amdgcn_sched_barrier(0);
    }

#pragma unroll
    for (int j = 0; j < 4; j++) {
        const int gc = wave * 64 + 16 * j + l16;
        const float bv = bf2f(bias[gc]);
#pragma unroll
        for (int i = 0; i < 4; i++) {
#pragma unroll
            for (int rr = 0; rr < 4; rr++) {
                int gr = m0 + 16 * i + quad * 4 + rr;
                if (gr < M) C[(size_t)gr * 256 + gc] = f2bf(acc[i][j][rr] + bv);
            }
        }
    }
}

// ---- CONV GEMM, weight-stationary (R6-verified): B staged to LDS once,
// A streamed in 32-row chunks, grid=256 persistent, 1 block/CU.
__global__ __launch_bounds__(512, 1) void gemm_ws(
    const unsigned short* __restrict__ A,   // [M,256] bf16
    const unsigned short* __restrict__ Bt,  // [256,256] bf16 [col][k]
    const float* __restrict__ prescale,     // dinv
    unsigned short* __restrict__ C, int M)
{
    __shared__ __align__(16) unsigned short Bs[256 * 256];       // 128 KB
    __shared__ __align__(16) unsigned short As[WSCHUNK * 256];   // 16 KB

    const int t = threadIdx.x;            // 0..511
    const int wave = t >> 6, lane = t & 63;
    const int quad = lane >> 4, l16 = lane & 15;
    const int rf = wave & 1;              // 16-row group within chunk
    const int cg = wave >> 1;             // 64-col group

    for (int it = 0; it < 16; ++it) {
        int id = it * 512 + t;
        int col = id >> 5, p = id & 31;
        int l = p ^ (col & 31);
        gload_lds16(Bt + col * 256 + l * 8, (char*)Bs + id * 16);
    }
    {
        const int rbs = blockIdx.x * WSCHUNK;
#pragma unroll
        for (int it = 0; it < 2; ++it) {
            int id = it * 512 + t;
            int row = id >> 5, p = id & 31;
            int l = p ^ (row & 31);
            int rg = min(rbs + row, M - 1);
            gload_lds16(A + (size_t)rg * 256 + l * 8, (char*)As + id * 16);
        }
    }
    __syncthreads();   // drains all DMA: B + A0 ready

    for (int c = blockIdx.x; c < NCHUNKS; c += 256) {
        f32x4 acc[4];
#pragma unroll
        for (int j = 0; j < 4; ++j) acc[j] = (f32x4){0.f, 0.f, 0.f, 0.f};

        const int arow = rf * 16 + l16;
#pragma unroll
        for (int ks = 0; ks < 8; ++ks) {
            const int s = ks * 4 + quad;
            bf16x8 af = *(const bf16x8*)((const char*)As + arow * 512 + ((s ^ (arow & 31)) * 16));
#pragma unroll
            for (int j = 0; j < 4; ++j) {
                const int col = cg * 64 + j * 16 + l16;
                bf16x8 bf = *(const bf16x8*)((const char*)Bs + col * 512 + ((s ^ (col & 31)) * 16));
                acc[j] = __builtin_amdgcn_mfma_f32_16x16x32_bf16(af, bf, acc[j], 0, 0, 0);
            }
        }
        __syncthreads();   // all waves done reading As

        const int cn = c + 256;
        if (cn < NCHUNKS) {
            const int rbs = cn * WSCHUNK;
#pragma unroll
            for (int it = 0; it < 2; ++it) {
                int id = it * 512 + t;
                int row = id >> 5, p = id & 31;
                int l = p ^ (row & 31);
                int rg = min(rbs + row, M - 1);
                gload_lds16(A + (size_t)rg * 256 + l * 8, (char*)As + id * 16);
            }
        }
        const int rb = c * WSCHUNK;
#pragma unroll
        for (int r = 0; r < 4; ++r) {
            const int gr = rb + rf * 16 + quad * 4 + r;
            if (gr < M) {
                const float sc = prescale[gr];
#pragma unroll
                for (int j = 0; j < 4; ++j) {
                    const int gc = cg * 64 + j * 16 + l16;
                    C[(size_t)gr * 256 + gc] = f2bf(acc[j][r] * sc);
                }
            }
        }
        __syncthreads();   // next A DMA drained; As ready for next iter
    }
}

// ------- fused: CSR gather + self-loop + bias + residual + ReLU + LayerNorm -------
// m is PRE-SCALED: m'[v] = dinv[v] * (h@W)[v], so
// h_new[v] = dinv[v] * (sum_{s in N(v)} m'[s] + m'[v]) + convB.
__global__ __launch_bounds__(256) void aggregate_ln(
    const int* __restrict__ rowptr, const int* __restrict__ csrc,
    const float* __restrict__ dinv, const unsigned short* __restrict__ m,
    const unsigned short* __restrict__ convB,
    const unsigned short* __restrict__ lnG, const unsigned short* __restrict__ lnB,
    unsigned short* __restrict__ h)
{
    const int half = threadIdx.x >> 5;
    const int lane = threadIdx.x & 31;
    const int node = blockIdx.x * 8 + half;  // NNODES % 8 == 0
    const float di = dinv[node];
    const size_t base = (size_t)node * DH + lane * 8;
    const size_t lo = lane * 8;

    float v0[8], v1[8];
    unpack8(*(const uint4*)(m + base), v0);   // self term m'[v]
#pragma unroll
    for (int j = 0; j < 8; j++) v1[j] = 0.f;

    const int kb = rowptr[node], ke = rowptr[node + 1];
    int k = kb;
    for (; k + 8 <= ke; k += 8) {
        int s0 = csrc[k],     s1 = csrc[k + 1], s2 = csrc[k + 2], s3 = csrc[k + 3];
        int s4 = csrc[k + 4], s5 = csrc[k + 5], s6 = csrc[k + 6], s7 = csrc[k + 7];
        uint4 r0 = *(const uint4*)(m + (size_t)s0 * DH + lo);
        uint4 r1 = *(const uint4*)(m + (size_t)s1 * DH + lo);
        uint4 r2 = *(const uint4*)(m + (size_t)s2 * DH + lo);
        uint4 r3 = *(const uint4*)(m + (size_t)s3 * DH + lo);
        uint4 r4 = *(const uint4*)(m + (size_t)s4 * DH + lo);
        uint4 r5 = *(const uint4*)(m + (size_t)s5 * DH + lo);
        uint4 r6 = *(const uint4*)(m + (size_t)s6 * DH + lo);
        uint4 r7 = *(const uint4*)(m + (size_t)s7 * DH + lo);
        acc8(r0, v0); acc8(r1, v1); acc8(r2, v0); acc8(r3, v1);
        acc8(r4, v0); acc8(r5, v1); acc8(r6, v0); acc8(r7, v1);
    }
    for (; k + 2 <= ke; k += 2) {
        int s0 = csrc[k], s1 = csrc[k + 1];
        uint4 r0 = *(const uint4*)(m + (size_t)s0 * DH + lo);
        uint4 r1 = *(const uint4*)(m + (size_t)s1 * DH + lo);
        acc8(r0, v0); acc8(r1, v1);
    }
    if (k < ke) {
        uint4 r0 = *(const uint4*)(m + (size_t)csrc[k] * DH + lo);
        acc8(r0, v0);
    }
#pragma unroll
    for (int j = 0; j < 8; j++) v0[j] = (v0[j] + v1[j]) * di;

    float hv[8], cv[8];
    unpack8(*(const uint4*)(h + base), hv);
    unpack8(*(const uint4*)(convB + lo), cv);
    float s1 = 0.f, s2 = 0.f;
#pragma unroll
    for (int j = 0; j < 8; j++) {
        v0[j] = fmaxf(v0[j] + cv[j] + hv[j], 0.f);
        s1 += v0[j];
        s2 += v0[j] * v0[j];
    }
#pragma unroll
    for (int off = 16; off > 0; off >>= 1) {
        s1 += __shfl_xor(s1, off, 32);
        s2 += __shfl_xor(s2, off, 32);
    }
    const float mu = s1 * (1.f / 256.f);
    const float var = s2 * (1.f / 256.f) - mu * mu;
    const float rs = rsqrtf(var + 1e-5f);
    float gv[8], bv[8];
    unpack8(*(const uint4*)(lnG + lo), gv);
    unpack8(*(const uint4*)(lnB + lo), bv);
    unsigned short o[8];
#pragma unroll
    for (int j = 0; j < 8; j++) o[j] = f2bf((v0[j] - mu) * rs * gv[j] + bv[j]);
    uint4 outp;
    outp.x = (unsigned)o[0] | ((unsigned)o[1] << 16);
    outp.y = (unsigned)o[2] | ((unsigned)o[3] << 16);
    outp.z = (unsigned)o[4] | ((unsigned)o[5] << 16);
    outp.w = (unsigned)o[6] | ((unsigned)o[7] << 16);
    *(uint4*)(h + base) = outp;
}

// ---- pooling: coalesced row reads + inline binary search on sorted batch ----
#define PSPLIT 8
__global__ __launch_bounds__(256) void pool_partial(
    const unsigned short* __restrict__ h, const int* __restrict__ batch,
    float* __restrict__ pg)
{
    __shared__ float red[8][DH];
    __shared__ int bounds[2];
    const int b = blockIdx.x >> 3, split = blockIdx.x & 7;
    if (threadIdx.x < 2) {
        int target = b + threadIdx.x;
        int lo = 0, hi = NNODES;
        while (lo < hi) { int mid = (lo + hi) >> 1; if (batch[mid] < target) lo = mid + 1; else hi = mid; }
        bounds[threadIdx.x] = lo;
    }
    __syncthreads();
    const int i0 = bounds[0], i1 = bounds[1];
    const int g = threadIdx.x >> 5, lane = threadIdx.x & 31;
    const int len = i1 - i0;
    const int c0 = i0 + (int)(((long)len * split) >> 3);
    const int c1 = i0 + (int)(((long)len * (split + 1)) >> 3);
    float mx[8];
#pragma unroll
    for (int j = 0; j < 8; ++j) mx[j] = -INFINITY;
    for (int r = c0 + g; r < c1; r += 8) {
        uint4 v = *(const uint4*)(h + (size_t)r * DH + lane * 8);
        float f[8];
        unpack8(v, f);
#pragma unroll
        for (int j = 0; j < 8; ++j) mx[j] = fmaxf(mx[j], f[j]);
    }
#pragma unroll
    for (int j = 0; j < 8; ++j) red[g][lane * 8 + j] = mx[j];
    __syncthreads();
    const int f = threadIdx.x;
    float m0 = fmaxf(fmaxf(red[0][f], red[1][f]), fmaxf(red[2][f], red[3][f]));
    float m1 = fmaxf(fmaxf(red[4][f], red[5][f]), fmaxf(red[6][f], red[7][f]));
    pg[(size_t)blockIdx.x * DH + f] = fmaxf(m0, m1);
}
__global__ __launch_bounds__(256) void pool_reduce(const float* __restrict__ pg,
                                                   float* __restrict__ g) {
    const int b = blockIdx.x, f = threadIdx.x;
    float mx = -INFINITY;
#pragma unroll
    for (int j = 0; j < PSPLIT; ++j) mx = fmaxf(mx, pg[(size_t)(b * PSPLIT + j) * DH + f]);
    g[b * DH + f] = mx;
}

// ---------------- classifier: out = relu(g@W1+b1)@W2+b2 ----------------
__global__ __launch_bounds__(256) void classifier(
    const float* __restrict__ g, const unsigned short* __restrict__ W1,
    const unsigned short* __restrict__ b1, const unsigned short* __restrict__ W2,
    const unsigned short* __restrict__ b2, void* __restrict__ outv,
    const int* __restrict__ flag)
{
    __shared__ float gz[DH];
    __shared__ float zz[DH];
    const int b = blockIdx.x, t = threadIdx.x;
    gz[t] = g[b * DH + t];
    __syncthreads();
    float s = bf2f(b1[t]);
    for (int k = 0; k < DH; ++k) s += gz[k] * bf2f(W1[k * DH + t]);
    zz[t] = fmaxf(s, 0.f);
    __syncthreads();
    if (t < NCLS) {
        float s2 = bf2f(b2[t]);
        for (int k = 0; k < DH; ++k) s2 += zz[k] * bf2f(W2[k * NCLS + t]);
        if (flag[0]) ((float*)outv)[b * NCLS + t] = s2;
        else ((unsigned short*)outv)[b * NCLS + t] = f2bf(s2);
    }
}

extern "C" void kernel_launch(void* const* d_in, const int* in_sizes, int n_in,
                              void* d_out, int out_size, void* d_ws, size_t ws_size,
                              hipStream_t stream)
{
    const void* x      = d_in[0];
    const int* ei      = (const int*)d_in[1];
    const int* batch   = (const int*)d_in[2];
    const void* Win    = d_in[3];
    const void* b_in   = d_in[4];
    const void* convW  = d_in[5];
    const void* convB  = d_in[6];
    const void* lnG    = d_in[7];
    const void* lnB    = d_in[8];
    const void* W1     = d_in[9];
    const void* b1     = d_in[10];
    const void* W2     = d_in[11];
    const void* b2     = d_in[12];

    // workspace layout (bytes), 16B aligned
    char* ws = (char*)d_ws;
    unsigned short* h   = (unsigned short*)(ws + 0);          // 25,600,000
    unsigned short* m   = (unsigned short*)(ws + 25600000);   // 25,600,000
    int* csrc           = (int*)(ws + 51200000);              //  3,200,000
    int* rowptr         = (int*)(ws + 54400000);              //    200,016
    int* cnt            = (int*)(ws + 54600016);              //    200,000
    int* cursor         = (int*)(ws + 54800016);              //    200,000
    float* dinv         = (float*)(ws + 55000016);            //    200,000
    unsigned short* cw  = (unsigned short*)(ws + 55200016);   //    138,768
    unsigned short* WinT= (unsigned short*)(ws + 55338784);   //    393,216
    unsigned short* WcT = (unsigned short*)(ws + 55732000);   //    393,216
    float* g            = (float*)(ws + 56125216);            //     65,536
    float* pg           = (float*)(ws + 56190752);            //    524,288
    int* bsum           = (int*)(ws + 56715312);              //        800
    int* boff           = (int*)(ws + 56716112);              //        800
    int* flag           = (int*)(ws + 56716912);              //         16
    const size_t NEED   = 56716928;
    if (ws_size < NEED) {
        fill_sentinel<<<(out_size / 2 + 255) / 256, 256, 0, stream>>>((float*)d_out, out_size / 2);
        return;
    }

    // canonical small weights (bf16 element offsets within cw)
    unsigned short* cBin   = cw + 0;
    unsigned short* cConvB = cw + 256;
    unsigned short* cLnG   = cw + 1024;
    unsigned short* cLnB   = cw + 1792;
    unsigned short* cW1    = cw + 2560;
    unsigned short* cW2    = cw + 68096;
    unsigned short* cB1    = cw + 69120;
    unsigned short* cB2    = cw + 69376;

    // ---- fused prep: dtype detect + canon + both transposes (1 launch) ----
    prep_fused<<<1808, 256, 0, stream>>>((const unsigned short*)x, Win, convW,
                                         b_in, convB, lnG, lnB, W1, W2, b1, b2,
                                         WinT, WcT, cw, flag);

    // ---- CSR build (dst-sorted) + degrees ----
    hipMemsetAsync(cnt, 0, 400000, stream);  // cnt AND cursor (contiguous)
    count_edges<<<(NEDGES + 255) / 256, 256, 0, stream>>>(ei, cnt);
    scan_local<<<SCAN_BLOCKS, 256, 0, stream>>>(cnt, rowptr, bsum);
    scan_bsum<<<1, 256, 0, stream>>>(bsum, boff);
    scan_finish<<<SCAN_BLOCKS, 256, 0, stream>>>(rowptr, boff, cnt, dinv);
    fill_csr<<<(NEDGES + 255) / 256, 256, 0, stream>>>(ei, rowptr, cursor, csrc);

    // ---- h = x @ W_in + b_in ----
    gemm_in<<<(NNODES + 63) / 64, 256, 0, stream>>>(x, flag, WinT, cBin, h, NNODES, DIN);

    // ---- 3 GCN layers: m' = dinv * (h@W)  then  h = LN(relu(dinv*(sum m') + b + h))
    for (int i = 0; i < 3; i++) {
        gemm_ws<<<256, 512, 0, stream>>>(h, WcT + i * DH * DH, dinv, m, NNODES);
        aggregate_ln<<<NNODES / 8, 256, 0, stream>>>(
            rowptr, csrc, dinv, m, cConvB + i * DH, cLnG + i * DH, cLnB + i * DH, h);
    }

    // ---- global max pool + classifier ----
    pool_partial<<<NGRAPHS * PSPLIT, 256, 0, stream>>>(h, batch, pg);
    pool_reduce<<<NGRAPHS, 256, 0, stream>>>(pg, g);
    classifier<<<NGRAPHS, 256, 0, stream>>>(g, cW1, cB1, cW2, cB2, d_out, flag);
}